// Round 7
// baseline (3341.385 us; speedup 1.0000x reference)
//
#include <hip/hip_runtime.h>
#include <cstddef>

// ---------------------------------------------------------------------------
// RelGraphConv GNN, 10 layers. Round 15: BK=64 DMA staging.
//   R14 post-mortem: READ rate is the universal ceiling (~0.6-1.1 TB/s);
//   writes stream freely (pass0's 3.3 TB/s was write-mix illusion). The R12
//   template drains vmcnt(0) at every 16 KB K-step -> ~900cy stall per step.
//   R15: BK 32->64 (parameter change inside the proven template): 32 KB in
//   flight per stage, half the drains per byte. LDS 64 KB -> 2 blocks/CU;
//   per-CU in-flight reads 45->64 KB. Keeps: W_loop fold into W_u1 (R14),
//   col-fastest grid (FETCH == ideal), fast_tanh epilogue.
// Z buffer (102 MB) aliases mid (dead during Z/segsum); ws ~210 MB.
// N=100000, E=600000, F=64, H=128, R=8.
// ---------------------------------------------------------------------------

#define HID 128
#define NREL 8
#define NL 10

typedef __attribute__((ext_vector_type(8))) __bf16 bf16x8;
typedef __attribute__((ext_vector_type(4))) float f32x4;

__device__ __forceinline__ float fast_tanh(float x) {
  float cx = fminf(fmaxf(x, -10.f), 10.f);
  float z = exp2f(cx * 2.8853900817779268f);
  return (z - 1.f) * __builtin_amdgcn_rcpf(z + 1.f);
}

// --- batched transpose + f32->bf16: tile z: W[zi][K][Nc] -> Wt[zo][Nc][K] ---
__global__ __launch_bounds__(256) void k_transpose(const float* __restrict__ W,
                                                   __bf16* __restrict__ Wt,
                                                   int K, int Nc,
                                                   int inDiv, int inScale, int inOff,
                                                   int outDiv, int outScale, int outOff) {
  __shared__ float t[32][33];
  int z = blockIdx.z;
  int zi = (z / inDiv) * inScale + (z % inDiv) + inOff;
  int zo = (z / outDiv) * outScale + (z % outDiv) + outOff;
  const float* Wz = W + (size_t)zi * K * Nc;
  __bf16* Wtz = Wt + (size_t)zo * K * Nc;
  int n0 = blockIdx.x * 32, k0 = blockIdx.y * 32;
#pragma unroll
  for (int i = 0; i < 4; i++) {
    int k = k0 + threadIdx.y + i * 8;
    int n = n0 + threadIdx.x;
    t[threadIdx.y + i * 8][threadIdx.x] = Wz[(size_t)k * Nc + n];
  }
  __syncthreads();
#pragma unroll
  for (int i = 0; i < 4; i++) {
    int n = n0 + threadIdx.y + i * 8;
    int k = k0 + threadIdx.x;
    Wtz[(size_t)n * K + k] = (__bf16)t[threadIdx.x][threadIdx.y + i * 8];
  }
}

// --- fold W_loop into wt_u1 (k<128 rows): wt[n][k] = Wu1[k][n] + sum_j
//     Wloop[k][j]*Wu1[128+j][n].  Runs AFTER k_transpose(W_u1) (same stream).
__global__ __launch_bounds__(256) void k_fold_wu1(const float* __restrict__ Wu1,
                                                  const float* __restrict__ Wloop,
                                                  __bf16* __restrict__ wt) {
  int l = blockIdx.y;
  int n0 = blockIdx.x * 32;
  const float* wu1 = Wu1 + (size_t)l * 256 * 256;
  const float* wl = Wloop + (size_t)l * 128 * 128;
  __bf16* wtl = wt + (size_t)l * 256 * 256;
  __shared__ float bot[128][33];
  for (int t = threadIdx.x; t < 128 * 32; t += 256) {
    int j = t >> 5, c = t & 31;
    bot[j][c] = wu1[(size_t)(128 + j) * 256 + n0 + c];
  }
  __syncthreads();
  int k = threadIdx.x & 127;
  int half = threadIdx.x >> 7;
  float acc[16];
#pragma unroll
  for (int c = 0; c < 16; c++) acc[c] = 0.f;
  for (int j = 0; j < 128; j++) {
    float w = wl[(size_t)k * 128 + j];
#pragma unroll
    for (int c = 0; c < 16; c++) acc[c] += w * bot[j][half * 16 + c];
  }
#pragma unroll
  for (int c = 0; c < 16; c++) {
    int n = n0 + half * 16 + c;
    wtl[(size_t)n * 256 + k] = (__bf16)(wu1[(size_t)k * 256 + n] + acc[c]);
  }
}

// --- f32 -> bf16 elementwise (n4 = count/4) ---
__global__ __launch_bounds__(256) void k_cvt(const float* __restrict__ x,
                                             __bf16* __restrict__ y, int n4) {
  int i = blockIdx.x * 256 + threadIdx.x;
  if (i < n4) {
    float4 f = ((const float4*)x)[i];
    __bf16 o[4] = {(__bf16)f.x, (__bf16)f.y, (__bf16)f.z, (__bf16)f.w};
    *(uint2*)(y + (size_t)i * 4) = *(uint2*)o;
  }
}

// ===================== dst-CSR build (once per launch) ======================
__global__ __launch_bounds__(256) void k_zero(int* __restrict__ p, int n) {
  for (int i = blockIdx.x * 256 + threadIdx.x; i < n; i += gridDim.x * 256) p[i] = 0;
}

__global__ __launch_bounds__(256) void k_hist_row(const int* __restrict__ dst,
                                                  int E, int* __restrict__ rowCnt) {
  int e = blockIdx.x * 256 + threadIdx.x;
  if (e < E) atomicAdd(&rowCnt[dst[e]], 1);
}

// --- hierarchical prefix scan over rowCnt[0..nb) ---------------------------
__global__ __launch_bounds__(256) void k_scan_part(const int* __restrict__ rowCnt,
                                                   int nb, int* __restrict__ thrPre,
                                                   int* __restrict__ blkSum) {
  __shared__ int sdata[256];
  int tid = threadIdx.x;
  int gtid = blockIdx.x * 256 + tid;
  int tot = gridDim.x * 256;
  int chunk = (nb + tot - 1) / tot;
  int lo = gtid * chunk, hi = min(nb, lo + chunk);
  int s = 0;
  for (int i = lo; i < hi; i++) s += rowCnt[i];
  sdata[tid] = s;
  __syncthreads();
#pragma unroll
  for (int off = 1; off < 256; off <<= 1) {
    int t = (tid >= off) ? sdata[tid - off] : 0;
    __syncthreads();
    sdata[tid] += t;
    __syncthreads();
  }
  thrPre[gtid] = sdata[tid] - s;
  if (tid == 255) blkSum[blockIdx.x] = sdata[255];
}

__global__ __launch_bounds__(256) void k_scan_mid(const int* __restrict__ blkSum,
                                                  int nblk, int nb,
                                                  int* __restrict__ blkOff,
                                                  int* __restrict__ rowStart) {
  __shared__ int part[256];
  int tid = threadIdx.x;
  part[tid] = (tid < nblk) ? blkSum[tid] : 0;
  __syncthreads();
  if (tid == 0) {
    int a = 0;
    for (int i = 0; i < nblk; i++) { int v = part[i]; part[i] = a; a += v; }
    rowStart[nb] = a;
  }
  __syncthreads();
  if (tid < nblk) blkOff[tid] = part[tid];
}

__global__ __launch_bounds__(256) void k_scan_fin(const int* __restrict__ rowCnt,
                                                  int nb,
                                                  const int* __restrict__ thrPre,
                                                  const int* __restrict__ blkOff,
                                                  int* __restrict__ rowStart,
                                                  int* __restrict__ rowCur) {
  int tid = threadIdx.x;
  int gtid = blockIdx.x * 256 + tid;
  int tot = gridDim.x * 256;
  int chunk = (nb + tot - 1) / tot;
  int lo = gtid * chunk, hi = min(nb, lo + chunk);
  int run = blkOff[blockIdx.x] + thrPre[gtid];
  for (int i = lo; i < hi; i++) {
    rowStart[i] = run;
    rowCur[i] = run;
    run += rowCnt[i];
  }
}

// pack: src (17 bits) | etype << 17
__global__ __launch_bounds__(256) void k_place_row(const int* __restrict__ et,
                                                   const int* __restrict__ src,
                                                   const int* __restrict__ dst,
                                                   int* __restrict__ rowCur,
                                                   int* __restrict__ epk, int E) {
  int e = blockIdx.x * 256 + threadIdx.x;
  if (e < E) {
    int p = atomicAdd(&rowCur[dst[e]], 1);
    epk[p] = src[e] | (et[e] << 17);
  }
}

// ========================= CSR segment-sum kernel ===========================
// 16 lanes per dst row. Init: b_rel_l (pass 0) else msgb (pass 1).
__global__ __launch_bounds__(256) void seg_sum(
    const __bf16* __restrict__ Z, const int* __restrict__ rowStart,
    const int* __restrict__ epk, const float* __restrict__ b_rel_l,
    __bf16* __restrict__ msgb, int N, int relBase, int zW) {
  int t16 = threadIdx.x & 15;
  int d = blockIdx.x * 16 + (threadIdx.x >> 4);
  if (d >= N) return;

  float acc[8];
  if (b_rel_l) {
#pragma unroll
    for (int z = 0; z < 8; z++) acc[z] = b_rel_l[t16 * 8 + z];
  } else {
    bf16x8 mv = *(const bf16x8*)(msgb + (size_t)d * HID + t16 * 8);
#pragma unroll
    for (int z = 0; z < 8; z++) acc[z] = (float)mv[z];
  }

  int lo = rowStart[d], hi = rowStart[d + 1];
  for (int e = lo; e < hi; e++) {
    int p = epk[e];
    int rr = (p >> 17) - relBase;
    if ((unsigned)rr < 4u) {
      bf16x8 v = *(const bf16x8*)(Z + (size_t)(p & 0x1FFFF) * zW + rr * HID + t16 * 8);
#pragma unroll
      for (int z = 0; z < 8; z++) acc[z] += (float)v[z];
    }
  }

  bf16x8 o;
#pragma unroll
  for (int z = 0; z < 8; z++) o[z] = (__bf16)acc[z];
  *(bf16x8*)(msgb + (size_t)d * HID + t16 * 8) = o;
}

// ---------------------------------------------------------------------------
// DMA-staged bf16 MFMA GEMM, BK=64: C = act(concat(A0,A1) @ B + bias)
//   128x128 C-tile, 256 threads. Per K-step: 128x64 A and B tiles (16 KB
//   each) staged via global_load_lds (16B chunks, linear LDS), double
//   buffered; stage(k+1) issued before compute(k); one __syncthreads/step.
//   Tile = 1024 chunks; wave w issues 4 DMA insts/operand (chunks
//   w*256 + j*64 + lane). grid: blockIdx.x = column tile (fastest).
// ---------------------------------------------------------------------------
template <int K, int K0, int MINW>
__global__ __launch_bounds__(256, MINW) void gemm_lds(
    const __bf16* __restrict__ A0, const __bf16* __restrict__ A1,
    const __bf16* __restrict__ Bt, const float* __restrict__ bias,
    __bf16* __restrict__ Cb, float* __restrict__ Cf,
    int M, int Nc, int act) {
  constexpr int NS = K / 64;
  constexpr int NS0 = K0 / 64;
  constexpr int K1 = (K - K0) > 0 ? (K - K0) : 1;
  __shared__ __bf16 As[2][128][64];
  __shared__ __bf16 Bs[2][128][64];

  const int tid = threadIdx.x;
  const int m0 = blockIdx.y * 128;
  const int bn0 = blockIdx.x * 128;
  const int w = tid >> 6;
  const int lane = tid & 63;

  // chunk c (16B) -> row c>>3, slot c&7; this wave: c = w*256 + j*64 + lane
  int rr_[4], ss_[4];
#pragma unroll
  for (int j = 0; j < 4; j++) {
    int c = w * 256 + j * 64 + lane;
    rr_[j] = c >> 3;
    ss_[j] = c & 7;
  }

  auto stage_step = [&](int b, int ks) {
#pragma unroll
    for (int j = 0; j < 4; j++) {
      const __bf16* gB = Bt + (size_t)(bn0 + rr_[j]) * K + ks * 64 + ss_[j] * 8;
      __builtin_amdgcn_global_load_lds(
          (const __attribute__((address_space(1))) void*)gB,
          (__attribute__((address_space(3))) void*)(&Bs[b][0][0] + (w * 4 + j) * 512),
          16, 0, 0);
    }
    if (ks < NS0) {
#pragma unroll
      for (int j = 0; j < 4; j++) {
        const __bf16* gA = A0 + (size_t)(m0 + rr_[j]) * K0 + ks * 64 + ss_[j] * 8;
        __builtin_amdgcn_global_load_lds(
            (const __attribute__((address_space(1))) void*)gA,
            (__attribute__((address_space(3))) void*)(&As[b][0][0] + (w * 4 + j) * 512),
            16, 0, 0);
      }
    } else {
#pragma unroll
      for (int j = 0; j < 4; j++) {
        const __bf16* gA = A1 + (size_t)(m0 + rr_[j]) * K1 + (ks - NS0) * 64 + ss_[j] * 8;
        __builtin_amdgcn_global_load_lds(
            (const __attribute__((address_space(1))) void*)gA,
            (__attribute__((address_space(3))) void*)(&As[b][0][0] + (w * 4 + j) * 512),
            16, 0, 0);
      }
    }
  };

  const int ml = lane & 15, q = lane >> 4;
  const int wr = (w >> 1) * 64, wc = (w & 1) * 64;

  f32x4 acc[4][4];
#pragma unroll
  for (int i = 0; i < 4; i++)
#pragma unroll
    for (int j = 0; j < 4; j++)
#pragma unroll
      for (int r = 0; r < 4; r++) acc[i][j][r] = 0.f;

  stage_step(0, 0);
  __syncthreads();  // implicit vmcnt(0): buffer 0 ready

#pragma unroll
  for (int ks = 0; ks < NS; ks++) {
    const int cur = ks & 1;
    if (ks + 1 < NS) stage_step(cur ^ 1, ks + 1);  // async DMA, in flight
#pragma unroll
    for (int kk = 0; kk < 2; kk++) {
      bf16x8 af[4], bfr[4];
#pragma unroll
      for (int i = 0; i < 4; i++)
        af[i] = *(const bf16x8*)(&As[cur][wr + i * 16 + ml][kk * 32 + q * 8]);
#pragma unroll
      for (int j = 0; j < 4; j++)
        bfr[j] = *(const bf16x8*)(&Bs[cur][wc + j * 16 + ml][kk * 32 + q * 8]);
#pragma unroll
      for (int i = 0; i < 4; i++)
#pragma unroll
        for (int j = 0; j < 4; j++)
          acc[i][j] = __builtin_amdgcn_mfma_f32_16x16x32_bf16(af[i], bfr[j],
                                                              acc[i][j], 0, 0, 0);
    }
    __syncthreads();  // drains stage(ks+1) DMA; protects buf reuse
  }

  // --- epilogue ---
#pragma unroll
  for (int i = 0; i < 4; i++) {
#pragma unroll
    for (int r = 0; r < 4; r++) {
      int grow = m0 + wr + i * 16 + q * 4 + r;
      if (grow >= M) continue;
#pragma unroll
      for (int j = 0; j < 4; j++) {
        int col = bn0 + wc + j * 16 + ml;
        float v = acc[i][j][r];
        if (bias) v += bias[col];
        if (act) v = fast_tanh(v);
        if (Cb) Cb[(size_t)grow * Nc + col] = (__bf16)v;
        if (Cf) Cf[(size_t)grow * Nc + col] = v;
      }
    }
  }
}

extern "C" void kernel_launch(void* const* d_in, const int* in_sizes, int n_in,
                              void* d_out, int out_size, void* d_ws, size_t ws_size,
                              hipStream_t stream) {
  const float* feats  = (const float*)d_in[0];
  const int*   src    = (const int*)d_in[1];
  const int*   dst    = (const int*)d_in[2];
  const int*   etype  = (const int*)d_in[3];
  const float* W_in   = (const float*)d_in[4];
  const float* b_in   = (const float*)d_in[5];
  const float* W_rel  = (const float*)d_in[6];
  const float* W_loop = (const float*)d_in[7];
  const float* b_rel  = (const float*)d_in[8];
  const float* W_u1   = (const float*)d_in[9];
  const float* b_u1   = (const float*)d_in[10];
  const float* W_u2   = (const float*)d_in[11];
  const float* b_u2   = (const float*)d_in[12];

  const int E = in_sizes[1];
  const int N = in_sizes[0] / 64;
  const int TS = HID * HID;

  // --- workspace layout (~210 MB) ---
  __bf16* xb0  = (__bf16*)d_ws;                       // N*128
  __bf16* xb1  = xb0 + (size_t)N * HID;               // N*128
  __bf16* msgb = xb1 + (size_t)N * HID;               // N*128
  __bf16* U    = msgb + (size_t)N * HID;              // N*640 (Z | mid | featsb)
  __bf16* Z    = U;
  __bf16* mid  = U;
  __bf16* featsb = U;
  __bf16* wt_in = U + (size_t)N * 640;                // [128][64]
  __bf16* wt_z0 = wt_in + 128 * 64;                   // [10][4][128][128]
  __bf16* wt_z1 = wt_z0 + (size_t)10 * 4 * TS;        // [10][4][128][128]
  __bf16* wt_u1 = wt_z1 + (size_t)10 * 4 * TS;        // [10][256][256]
  __bf16* wt_u2 = wt_u1 + (size_t)10 * 256 * 256;     // [10][128][384]
  int* rowCnt   = (int*)(wt_u2 + (size_t)10 * 128 * 384); // N
  int* rowStart = rowCnt + N;                         // N+1
  int* rowCur   = rowStart + N + 1;                   // N
  int* epk      = rowCur + N;                         // E
  int* thrPre   = epk + E;                            // 256*256
  int* blkSum   = thrPre + 256 * 256;                 // 256
  int* blkOff   = blkSum + 256;                       // 256

  // --- weight transpose+convert ---
  k_transpose<<<dim3(4, 2, 1), dim3(32, 8), 0, stream>>>(W_in, wt_in, 64, 128,
                                                         1, 1, 0, 1, 1, 0);
  // W_rel r<4 -> wt_z0 tiles (l*4 + r)
  k_transpose<<<dim3(4, 4, 40), dim3(32, 8), 0, stream>>>(W_rel, wt_z0, 128, 128,
                                                          4, 8, 0, 4, 4, 0);
  // W_rel r>=4 -> wt_z1 tiles (l*4 + r-4)
  k_transpose<<<dim3(4, 4, 40), dim3(32, 8), 0, stream>>>(W_rel, wt_z1, 128, 128,
                                                          4, 8, 4, 4, 4, 0);
  // W_u1, W_u2
  k_transpose<<<dim3(8, 8, 10), dim3(32, 8), 0, stream>>>(W_u1, wt_u1, 256, 256,
                                                          1, 1, 0, 1, 1, 0);
  // fold W_loop into wt_u1 rows k<128 (after transpose; same stream)
  k_fold_wu1<<<dim3(8, 10), dim3(256), 0, stream>>>(W_u1, W_loop, wt_u1);
  k_transpose<<<dim3(4, 12, 10), dim3(32, 8), 0, stream>>>(W_u2, wt_u2, 384, 128,
                                                           1, 1, 0, 1, 1, 0);
  k_cvt<<<(N * 64 / 4 + 255) / 256, 256, 0, stream>>>(feats, featsb, N * 64 / 4);

  // --- dst-CSR build ---
  k_zero<<<128, 256, 0, stream>>>(rowCnt, N);
  k_hist_row<<<(E + 255) / 256, 256, 0, stream>>>(dst, E, rowCnt);
  k_scan_part<<<256, 256, 0, stream>>>(rowCnt, N, thrPre, blkSum);
  k_scan_mid<<<1, 256, 0, stream>>>(blkSum, 256, N, blkOff, rowStart);
  k_scan_fin<<<256, 256, 0, stream>>>(rowCnt, N, thrPre, blkOff, rowStart, rowCur);
  k_place_row<<<(E + 255) / 256, 256, 0, stream>>>(etype, src, dst, rowCur, epk, E);

  const dim3 blk(256);
  const int gm = (N + 127) / 128;
  const dim3 gseg((N + 15) / 16);

  // input projection: x0 = tanh(featsb @ W_in + b_in)
  gemm_lds<64, 64, 2><<<dim3(1, gm), blk, 0, stream>>>(
      featsb, featsb, wt_in, b_in, xb0, nullptr, N, HID, 1);

  for (int l = 0; l < NL; l++) {
    const __bf16* xin = (l & 1) ? xb1 : xb0;
    __bf16* xout = (l & 1) ? xb0 : xb1;

    // pass 0: Z = xin @ [W_0..3]  (N x 512; W_loop folded into wt_u1)
    gemm_lds<128, 128, 2><<<dim3(4, gm), blk, 0, stream>>>(
        xin, xin, wt_z0 + (size_t)l * 4 * TS, nullptr, Z, nullptr, N, 512, 0);
    // seg0: msg = b_rel + sum(r<4) edges
    seg_sum<<<gseg, blk, 0, stream>>>(Z, rowStart, epk, b_rel + (size_t)l * HID,
                                      msgb, N, 0, 512);
    // pass 1: Z = xin @ [W_4..7]  (N x 512)
    gemm_lds<128, 128, 2><<<dim3(4, gm), blk, 0, stream>>>(
        xin, xin, wt_z1 + (size_t)l * 4 * TS, nullptr, Z, nullptr, N, 512, 0);
    // seg1: msg += sum(r>=4) edges
    seg_sum<<<gseg, blk, 0, stream>>>(Z, rowStart, epk, nullptr,
                                      msgb, N, 4, 512);

    // mid = tanh([x | msg] @ Wu1_eff[l] + b_u1[l])   (mid aliases Z)
    gemm_lds<256, 128, 2><<<dim3(2, gm), blk, 0, stream>>>(
        xin, msgb, wt_u1 + (size_t)l * 256 * 256, b_u1 + (size_t)l * 256,
        mid, nullptr, N, 256, 1);

    // x' = tanh([x | mid] @ W_u2[l] + b_u2[l]); last layer -> f32 d_out
    gemm_lds<384, 128, 2><<<dim3(1, gm), blk, 0, stream>>>(
        xin, mid, wt_u2 + (size_t)l * HID * 384, b_u2 + (size_t)l * HID,
        (l == NL - 1) ? nullptr : xout,
        (l == NL - 1) ? (float*)d_out : nullptr,
        N, HID, 1);
  }
}

// Round 8
// 2971.458 us; speedup vs baseline: 1.1245x; 1.1245x over previous
//
#include <hip/hip_runtime.h>
#include <cstddef>

// ---------------------------------------------------------------------------
// RelGraphConv GNN, 10 layers. Round 16: fused U1+U2 (mid stays in LDS).
//   R15 (BK=64) regressed (occupancy 35->17.6%, conflicts 3x) -> reverted to
//   the proven R14 BK=32 DMA GEMM for pass0/pass1/proj.
//   NEW fused_u: per 128-row block, [x|msg] reg-staged into LDS A[128][392]
//   (16B-aligned rows, 2-way-free conflicts); phase 1 computes
//   mid=tanh([x|msg]@Wu1e+b) col-tile c=1 then c=0, writing mid into A cols
//   128..383 (c=0 overwrites the msg half only after its final read, which
//   the K-loop's trailing barrier guarantees); phase 2 computes
//   out=tanh([x|mid]@Wu2+b) streaming only weights (L2-resident) via the
//   proven BK=32 global_load_lds double-buffer. Kills the mid HBM round-trip
//   + x re-read: -128 MB/layer.
// Keeps: W_loop fold into W_u1 (R14), col-fastest grid, fast_tanh.
// N=100000, E=600000, F=64, H=128, R=8.
// ---------------------------------------------------------------------------

#define HID 128
#define NREL 8
#define NL 10

typedef __attribute__((ext_vector_type(8))) __bf16 bf16x8;
typedef __attribute__((ext_vector_type(4))) float f32x4;

__device__ __forceinline__ float fast_tanh(float x) {
  float cx = fminf(fmaxf(x, -10.f), 10.f);
  float z = exp2f(cx * 2.8853900817779268f);
  return (z - 1.f) * __builtin_amdgcn_rcpf(z + 1.f);
}

// --- batched transpose + f32->bf16: tile z: W[zi][K][Nc] -> Wt[zo][Nc][K] ---
__global__ __launch_bounds__(256) void k_transpose(const float* __restrict__ W,
                                                   __bf16* __restrict__ Wt,
                                                   int K, int Nc,
                                                   int inDiv, int inScale, int inOff,
                                                   int outDiv, int outScale, int outOff) {
  __shared__ float t[32][33];
  int z = blockIdx.z;
  int zi = (z / inDiv) * inScale + (z % inDiv) + inOff;
  int zo = (z / outDiv) * outScale + (z % outDiv) + outOff;
  const float* Wz = W + (size_t)zi * K * Nc;
  __bf16* Wtz = Wt + (size_t)zo * K * Nc;
  int n0 = blockIdx.x * 32, k0 = blockIdx.y * 32;
#pragma unroll
  for (int i = 0; i < 4; i++) {
    int k = k0 + threadIdx.y + i * 8;
    int n = n0 + threadIdx.x;
    t[threadIdx.y + i * 8][threadIdx.x] = Wz[(size_t)k * Nc + n];
  }
  __syncthreads();
#pragma unroll
  for (int i = 0; i < 4; i++) {
    int n = n0 + threadIdx.y + i * 8;
    int k = k0 + threadIdx.x;
    Wtz[(size_t)n * K + k] = (__bf16)t[threadIdx.x][threadIdx.y + i * 8];
  }
}

// --- fold W_loop into wt_u1 (k<128 rows): wt[n][k] = Wu1[k][n] + sum_j
//     Wloop[k][j]*Wu1[128+j][n]. Runs AFTER k_transpose(W_u1).
__global__ __launch_bounds__(256) void k_fold_wu1(const float* __restrict__ Wu1,
                                                  const float* __restrict__ Wloop,
                                                  __bf16* __restrict__ wt) {
  int l = blockIdx.y;
  int n0 = blockIdx.x * 32;
  const float* wu1 = Wu1 + (size_t)l * 256 * 256;
  const float* wl = Wloop + (size_t)l * 128 * 128;
  __bf16* wtl = wt + (size_t)l * 256 * 256;
  __shared__ float bot[128][33];
  for (int t = threadIdx.x; t < 128 * 32; t += 256) {
    int j = t >> 5, c = t & 31;
    bot[j][c] = wu1[(size_t)(128 + j) * 256 + n0 + c];
  }
  __syncthreads();
  int k = threadIdx.x & 127;
  int half = threadIdx.x >> 7;
  float acc[16];
#pragma unroll
  for (int c = 0; c < 16; c++) acc[c] = 0.f;
  for (int j = 0; j < 128; j++) {
    float w = wl[(size_t)k * 128 + j];
#pragma unroll
    for (int c = 0; c < 16; c++) acc[c] += w * bot[j][half * 16 + c];
  }
#pragma unroll
  for (int c = 0; c < 16; c++) {
    int n = n0 + half * 16 + c;
    wtl[(size_t)n * 256 + k] = (__bf16)(wu1[(size_t)k * 256 + n] + acc[c]);
  }
}

// --- f32 -> bf16 elementwise (n4 = count/4) ---
__global__ __launch_bounds__(256) void k_cvt(const float* __restrict__ x,
                                             __bf16* __restrict__ y, int n4) {
  int i = blockIdx.x * 256 + threadIdx.x;
  if (i < n4) {
    float4 f = ((const float4*)x)[i];
    __bf16 o[4] = {(__bf16)f.x, (__bf16)f.y, (__bf16)f.z, (__bf16)f.w};
    *(uint2*)(y + (size_t)i * 4) = *(uint2*)o;
  }
}

// ===================== dst-CSR build (once per launch) ======================
__global__ __launch_bounds__(256) void k_zero(int* __restrict__ p, int n) {
  for (int i = blockIdx.x * 256 + threadIdx.x; i < n; i += gridDim.x * 256) p[i] = 0;
}

__global__ __launch_bounds__(256) void k_hist_row(const int* __restrict__ dst,
                                                  int E, int* __restrict__ rowCnt) {
  int e = blockIdx.x * 256 + threadIdx.x;
  if (e < E) atomicAdd(&rowCnt[dst[e]], 1);
}

// --- hierarchical prefix scan over rowCnt[0..nb) ---------------------------
__global__ __launch_bounds__(256) void k_scan_part(const int* __restrict__ rowCnt,
                                                   int nb, int* __restrict__ thrPre,
                                                   int* __restrict__ blkSum) {
  __shared__ int sdata[256];
  int tid = threadIdx.x;
  int gtid = blockIdx.x * 256 + tid;
  int tot = gridDim.x * 256;
  int chunk = (nb + tot - 1) / tot;
  int lo = gtid * chunk, hi = min(nb, lo + chunk);
  int s = 0;
  for (int i = lo; i < hi; i++) s += rowCnt[i];
  sdata[tid] = s;
  __syncthreads();
#pragma unroll
  for (int off = 1; off < 256; off <<= 1) {
    int t = (tid >= off) ? sdata[tid - off] : 0;
    __syncthreads();
    sdata[tid] += t;
    __syncthreads();
  }
  thrPre[gtid] = sdata[tid] - s;
  if (tid == 255) blkSum[blockIdx.x] = sdata[255];
}

__global__ __launch_bounds__(256) void k_scan_mid(const int* __restrict__ blkSum,
                                                  int nblk, int nb,
                                                  int* __restrict__ blkOff,
                                                  int* __restrict__ rowStart) {
  __shared__ int part[256];
  int tid = threadIdx.x;
  part[tid] = (tid < nblk) ? blkSum[tid] : 0;
  __syncthreads();
  if (tid == 0) {
    int a = 0;
    for (int i = 0; i < nblk; i++) { int v = part[i]; part[i] = a; a += v; }
    rowStart[nb] = a;
  }
  __syncthreads();
  if (tid < nblk) blkOff[tid] = part[tid];
}

__global__ __launch_bounds__(256) void k_scan_fin(const int* __restrict__ rowCnt,
                                                  int nb,
                                                  const int* __restrict__ thrPre,
                                                  const int* __restrict__ blkOff,
                                                  int* __restrict__ rowStart,
                                                  int* __restrict__ rowCur) {
  int tid = threadIdx.x;
  int gtid = blockIdx.x * 256 + tid;
  int tot = gridDim.x * 256;
  int chunk = (nb + tot - 1) / tot;
  int lo = gtid * chunk, hi = min(nb, lo + chunk);
  int run = blkOff[blockIdx.x] + thrPre[gtid];
  for (int i = lo; i < hi; i++) {
    rowStart[i] = run;
    rowCur[i] = run;
    run += rowCnt[i];
  }
}

// pack: src (17 bits) | etype << 17
__global__ __launch_bounds__(256) void k_place_row(const int* __restrict__ et,
                                                   const int* __restrict__ src,
                                                   const int* __restrict__ dst,
                                                   int* __restrict__ rowCur,
                                                   int* __restrict__ epk, int E) {
  int e = blockIdx.x * 256 + threadIdx.x;
  if (e < E) {
    int p = atomicAdd(&rowCur[dst[e]], 1);
    epk[p] = src[e] | (et[e] << 17);
  }
}

// ========================= CSR segment-sum kernel ===========================
__global__ __launch_bounds__(256) void seg_sum(
    const __bf16* __restrict__ Z, const int* __restrict__ rowStart,
    const int* __restrict__ epk, const float* __restrict__ b_rel_l,
    __bf16* __restrict__ msgb, int N, int relBase, int zW) {
  int t16 = threadIdx.x & 15;
  int d = blockIdx.x * 16 + (threadIdx.x >> 4);
  if (d >= N) return;

  float acc[8];
  if (b_rel_l) {
#pragma unroll
    for (int z = 0; z < 8; z++) acc[z] = b_rel_l[t16 * 8 + z];
  } else {
    bf16x8 mv = *(const bf16x8*)(msgb + (size_t)d * HID + t16 * 8);
#pragma unroll
    for (int z = 0; z < 8; z++) acc[z] = (float)mv[z];
  }

  int lo = rowStart[d], hi = rowStart[d + 1];
  for (int e = lo; e < hi; e++) {
    int p = epk[e];
    int rr = (p >> 17) - relBase;
    if ((unsigned)rr < 4u) {
      bf16x8 v = *(const bf16x8*)(Z + (size_t)(p & 0x1FFFF) * zW + rr * HID + t16 * 8);
#pragma unroll
      for (int z = 0; z < 8; z++) acc[z] += (float)v[z];
    }
  }

  bf16x8 o;
#pragma unroll
  for (int z = 0; z < 8; z++) o[z] = (__bf16)acc[z];
  *(bf16x8*)(msgb + (size_t)d * HID + t16 * 8) = o;
}

// ---------------------------------------------------------------------------
// DMA-staged bf16 MFMA GEMM (R12/R14-proven, BK=32):
//   C = act(concat(A0,A1) @ B + bias). 128x128 C-tile, 256 threads.
// ---------------------------------------------------------------------------
template <int K, int K0, int MINW>
__global__ __launch_bounds__(256, MINW) void gemm_lds(
    const __bf16* __restrict__ A0, const __bf16* __restrict__ A1,
    const __bf16* __restrict__ Bt, const float* __restrict__ bias,
    __bf16* __restrict__ Cb, float* __restrict__ Cf,
    int M, int Nc, int act) {
  constexpr int NS = K / 32;
  constexpr int NS0 = K0 / 32;
  constexpr int K1 = (K - K0) > 0 ? (K - K0) : 1;
  __shared__ __bf16 As[2][128][32];
  __shared__ __bf16 Bs[2][128][32];

  const int tid = threadIdx.x;
  const int m0 = blockIdx.y * 128;
  const int bn0 = blockIdx.x * 128;
  const int w = tid >> 6;
  const int lane = tid & 63;

  const int cA = w * 128 + lane;
  const int r0 = cA >> 2, s0 = cA & 3;
  const int r1 = (cA + 64) >> 2, s1 = (cA + 64) & 3;

  auto stage_step = [&](int b, int ks) {
    {
      const __bf16* g0 = Bt + (size_t)(bn0 + r0) * K + ks * 32 + s0 * 8;
      __builtin_amdgcn_global_load_lds(
          (const __attribute__((address_space(1))) void*)g0,
          (__attribute__((address_space(3))) void*)(&Bs[b][0][0] + (w * 2 + 0) * 512),
          16, 0, 0);
      const __bf16* g1 = Bt + (size_t)(bn0 + r1) * K + ks * 32 + s1 * 8;
      __builtin_amdgcn_global_load_lds(
          (const __attribute__((address_space(1))) void*)g1,
          (__attribute__((address_space(3))) void*)(&Bs[b][0][0] + (w * 2 + 1) * 512),
          16, 0, 0);
    }
    if (ks < NS0) {
      const __bf16* g0 = A0 + (size_t)(m0 + r0) * K0 + ks * 32 + s0 * 8;
      __builtin_amdgcn_global_load_lds(
          (const __attribute__((address_space(1))) void*)g0,
          (__attribute__((address_space(3))) void*)(&As[b][0][0] + (w * 2 + 0) * 512),
          16, 0, 0);
      const __bf16* g1 = A0 + (size_t)(m0 + r1) * K0 + ks * 32 + s1 * 8;
      __builtin_amdgcn_global_load_lds(
          (const __attribute__((address_space(1))) void*)g1,
          (__attribute__((address_space(3))) void*)(&As[b][0][0] + (w * 2 + 1) * 512),
          16, 0, 0);
    } else {
      const __bf16* g0 = A1 + (size_t)(m0 + r0) * K1 + (ks - NS0) * 32 + s0 * 8;
      __builtin_amdgcn_global_load_lds(
          (const __attribute__((address_space(1))) void*)g0,
          (__attribute__((address_space(3))) void*)(&As[b][0][0] + (w * 2 + 0) * 512),
          16, 0, 0);
      const __bf16* g1 = A1 + (size_t)(m0 + r1) * K1 + (ks - NS0) * 32 + s1 * 8;
      __builtin_amdgcn_global_load_lds(
          (const __attribute__((address_space(1))) void*)g1,
          (__attribute__((address_space(3))) void*)(&As[b][0][0] + (w * 2 + 1) * 512),
          16, 0, 0);
    }
  };

  const int ml = lane & 15, q = lane >> 4;
  const int wr = (w >> 1) * 64, wc = (w & 1) * 64;

  f32x4 acc[4][4];
#pragma unroll
  for (int i = 0; i < 4; i++)
#pragma unroll
    for (int j = 0; j < 4; j++)
#pragma unroll
      for (int r = 0; r < 4; r++) acc[i][j][r] = 0.f;

  stage_step(0, 0);
  __syncthreads();

#pragma unroll
  for (int ks = 0; ks < NS; ks++) {
    const int cur = ks & 1;
    if (ks + 1 < NS) stage_step(cur ^ 1, ks + 1);
    bf16x8 af[4], bfr[4];
#pragma unroll
    for (int i = 0; i < 4; i++)
      af[i] = *(const bf16x8*)(&As[cur][wr + i * 16 + ml][q * 8]);
#pragma unroll
    for (int j = 0; j < 4; j++)
      bfr[j] = *(const bf16x8*)(&Bs[cur][wc + j * 16 + ml][q * 8]);
#pragma unroll
    for (int i = 0; i < 4; i++)
#pragma unroll
      for (int j = 0; j < 4; j++)
        acc[i][j] = __builtin_amdgcn_mfma_f32_16x16x32_bf16(af[i], bfr[j],
                                                            acc[i][j], 0, 0, 0);
    __syncthreads();
  }

#pragma unroll
  for (int i = 0; i < 4; i++) {
#pragma unroll
    for (int r = 0; r < 4; r++) {
      int grow = m0 + wr + i * 16 + q * 4 + r;
      if (grow >= M) continue;
#pragma unroll
      for (int j = 0; j < 4; j++) {
        int col = bn0 + wc + j * 16 + ml;
        float v = acc[i][j][r];
        if (bias) v += bias[col];
        if (act) v = fast_tanh(v);
        if (Cb) Cb[(size_t)grow * Nc + col] = (__bf16)v;
        if (Cf) Cf[(size_t)grow * Nc + col] = v;
      }
    }
  }
}

// ---------------------------------------------------------------------------
// Fused U1+U2: out = tanh([x | tanh([x|msg]@Wu1e + bu1)] @ Wu2 + bu2)
//   One 128-row block. A[128][392] LDS holds [x(0:128) | msg->mid(128:384)].
//   Phase 1 col-tile order c=1 then c=0 (c=0 overwrites the msg half only
//   after its last read, guaranteed by the K-loop's trailing barrier).
//   Weights streamed via BK=32 global_load_lds dbuf (L2-resident).
// ---------------------------------------------------------------------------
__global__ __launch_bounds__(256) void fused_u(
    const __bf16* __restrict__ xin, const __bf16* __restrict__ msgb,
    const __bf16* __restrict__ wu1, const float* __restrict__ bu1,
    const __bf16* __restrict__ wu2, const float* __restrict__ bu2,
    __bf16* __restrict__ Cb, float* __restrict__ Cf, int M) {
  constexpr int PA = 392;  // 784 B row stride: 16B-aligned, 2-way-free banks
  __shared__ __bf16 A[128][PA];
  __shared__ __bf16 Bs[2][128][32];

  const int tid = threadIdx.x;
  const int m0 = blockIdx.x * 128;
  const int w = tid >> 6, lane = tid & 63;
  const int ml = lane & 15, q = lane >> 4;
  const int wr = (w >> 1) * 64, wc = (w & 1) * 64;

  // ---- reg-staged A load: x -> cols 0:128, msg -> cols 128:256 ----
  {
    bf16x8 vx[8], vm[8];
    int rr8[8], cc8[8];
#pragma unroll
    for (int j = 0; j < 8; j++) {
      int c = j * 256 + tid;
      int r = c >> 4, c8 = (c & 15) * 8;
      int gr = m0 + r;
      if (gr >= M) gr = M - 1;
      rr8[j] = r;
      cc8[j] = c8;
      vx[j] = *(const bf16x8*)(xin + (size_t)gr * HID + c8);
      vm[j] = *(const bf16x8*)(msgb + (size_t)gr * HID + c8);
    }
#pragma unroll
    for (int j = 0; j < 8; j++) {
      *(bf16x8*)(&A[rr8[j]][cc8[j]]) = vx[j];
      *(bf16x8*)(&A[rr8[j]][128 + cc8[j]]) = vm[j];
    }
  }
  __syncthreads();

  // B-stage chunk geometry (8 KB tile = 512x16B; 2 DMA insts per wave)
  const int cB = w * 128 + lane;
  const int rB0 = cB >> 2, sB0 = cB & 3;
  const int rB1 = (cB + 64) >> 2, sB1 = (cB + 64) & 3;
  auto stageB = [&](int b, const __bf16* Wrow0, size_t kstride, int ks) {
    const __bf16* g0 = Wrow0 + (size_t)rB0 * kstride + ks * 32 + sB0 * 8;
    __builtin_amdgcn_global_load_lds(
        (const __attribute__((address_space(1))) void*)g0,
        (__attribute__((address_space(3))) void*)(&Bs[b][0][0] + (w * 2 + 0) * 512),
        16, 0, 0);
    const __bf16* g1 = Wrow0 + (size_t)rB1 * kstride + ks * 32 + sB1 * 8;
    __builtin_amdgcn_global_load_lds(
        (const __attribute__((address_space(1))) void*)g1,
        (__attribute__((address_space(3))) void*)(&Bs[b][0][0] + (w * 2 + 1) * 512),
        16, 0, 0);
  };

  // ---- phase 1: mid = tanh([x|msg] @ Wu1e + bu1) -> A cols 128..383 ----
#pragma unroll
  for (int ct = 1; ct >= 0; ct--) {
    const __bf16* Wc = wu1 + (size_t)(ct * 128) * 256;
    f32x4 acc[4][4];
#pragma unroll
    for (int i = 0; i < 4; i++)
#pragma unroll
      for (int j = 0; j < 4; j++)
#pragma unroll
        for (int r = 0; r < 4; r++) acc[i][j][r] = 0.f;

    stageB(0, Wc, 256, 0);
    __syncthreads();
#pragma unroll
    for (int ks = 0; ks < 8; ks++) {
      const int cur = ks & 1;
      if (ks + 1 < 8) stageB(cur ^ 1, Wc, 256, ks + 1);
      bf16x8 af[4], bfr[4];
#pragma unroll
      for (int i = 0; i < 4; i++)
        af[i] = *(const bf16x8*)(&A[wr + i * 16 + ml][ks * 32 + q * 8]);
#pragma unroll
      for (int j = 0; j < 4; j++)
        bfr[j] = *(const bf16x8*)(&Bs[cur][wc + j * 16 + ml][q * 8]);
#pragma unroll
      for (int i = 0; i < 4; i++)
#pragma unroll
        for (int j = 0; j < 4; j++)
          acc[i][j] = __builtin_amdgcn_mfma_f32_16x16x32_bf16(af[i], bfr[j],
                                                              acc[i][j], 0, 0, 0);
      __syncthreads();  // also: all waves done reading A before mid overwrite
    }
    // epilogue: mid -> LDS (cols 128 + ct*128 + ...)
#pragma unroll
    for (int i = 0; i < 4; i++) {
#pragma unroll
      for (int r = 0; r < 4; r++) {
        int row = wr + i * 16 + q * 4 + r;
#pragma unroll
        for (int j = 0; j < 4; j++) {
          int col = ct * 128 + wc + j * 16 + ml;
          float v = acc[i][j][r] + bu1[col];
          A[row][128 + col] = (__bf16)fast_tanh(v);
        }
      }
    }
    __syncthreads();  // mid writes visible before next phase reads
  }

  // ---- phase 2: out = tanh([x|mid] @ Wu2 + bu2) ----
  {
    f32x4 acc[4][4];
#pragma unroll
    for (int i = 0; i < 4; i++)
#pragma unroll
      for (int j = 0; j < 4; j++)
#pragma unroll
        for (int r = 0; r < 4; r++) acc[i][j][r] = 0.f;

    stageB(0, wu2, 384, 0);
    __syncthreads();
#pragma unroll
    for (int ks = 0; ks < 12; ks++) {
      const int cur = ks & 1;
      if (ks + 1 < 12) stageB(cur ^ 1, wu2, 384, ks + 1);
      bf16x8 af[4], bfr[4];
#pragma unroll
      for (int i = 0; i < 4; i++)
        af[i] = *(const bf16x8*)(&A[wr + i * 16 + ml][ks * 32 + q * 8]);
#pragma unroll
      for (int j = 0; j < 4; j++)
        bfr[j] = *(const bf16x8*)(&Bs[cur][wc + j * 16 + ml][q * 8]);
#pragma unroll
      for (int i = 0; i < 4; i++)
#pragma unroll
        for (int j = 0; j < 4; j++)
          acc[i][j] = __builtin_amdgcn_mfma_f32_16x16x32_bf16(af[i], bfr[j],
                                                              acc[i][j], 0, 0, 0);
      __syncthreads();
    }
#pragma unroll
    for (int i = 0; i < 4; i++) {
#pragma unroll
      for (int r = 0; r < 4; r++) {
        int grow = m0 + wr + i * 16 + q * 4 + r;
        if (grow >= M) continue;
#pragma unroll
        for (int j = 0; j < 4; j++) {
          int col = wc + j * 16 + ml;
          float v = fast_tanh(acc[i][j][r] + bu2[col]);
          if (Cb) Cb[(size_t)grow * HID + col] = (__bf16)v;
          if (Cf) Cf[(size_t)grow * HID + col] = v;
        }
      }
    }
  }
}

extern "C" void kernel_launch(void* const* d_in, const int* in_sizes, int n_in,
                              void* d_out, int out_size, void* d_ws, size_t ws_size,
                              hipStream_t stream) {
  const float* feats  = (const float*)d_in[0];
  const int*   src    = (const int*)d_in[1];
  const int*   dst    = (const int*)d_in[2];
  const int*   etype  = (const int*)d_in[3];
  const float* W_in   = (const float*)d_in[4];
  const float* b_in   = (const float*)d_in[5];
  const float* W_rel  = (const float*)d_in[6];
  const float* W_loop = (const float*)d_in[7];
  const float* b_rel  = (const float*)d_in[8];
  const float* W_u1   = (const float*)d_in[9];
  const float* b_u1   = (const float*)d_in[10];
  const float* W_u2   = (const float*)d_in[11];
  const float* b_u2   = (const float*)d_in[12];

  const int E = in_sizes[1];
  const int N = in_sizes[0] / 64;
  const int TS = HID * HID;

  // --- workspace layout (~210 MB) ---
  __bf16* xb0  = (__bf16*)d_ws;                       // N*128
  __bf16* xb1  = xb0 + (size_t)N * HID;               // N*128
  __bf16* msgb = xb1 + (size_t)N * HID;               // N*128
  __bf16* U    = msgb + (size_t)N * HID;              // N*640 (Z | featsb)
  __bf16* Z    = U;
  __bf16* featsb = U;
  __bf16* wt_in = U + (size_t)N * 640;                // [128][64]
  __bf16* wt_z0 = wt_in + 128 * 64;                   // [10][4][128][128]
  __bf16* wt_z1 = wt_z0 + (size_t)10 * 4 * TS;        // [10][4][128][128]
  __bf16* wt_u1 = wt_z1 + (size_t)10 * 4 * TS;        // [10][256][256]
  __bf16* wt_u2 = wt_u1 + (size_t)10 * 256 * 256;     // [10][128][384]
  int* rowCnt   = (int*)(wt_u2 + (size_t)10 * 128 * 384); // N
  int* rowStart = rowCnt + N;                         // N+1
  int* rowCur   = rowStart + N + 1;                   // N
  int* epk      = rowCur + N;                         // E
  int* thrPre   = epk + E;                            // 256*256
  int* blkSum   = thrPre + 256 * 256;                 // 256
  int* blkOff   = blkSum + 256;                       // 256

  // --- weight transpose+convert ---
  k_transpose<<<dim3(4, 2, 1), dim3(32, 8), 0, stream>>>(W_in, wt_in, 64, 128,
                                                         1, 1, 0, 1, 1, 0);
  k_transpose<<<dim3(4, 4, 40), dim3(32, 8), 0, stream>>>(W_rel, wt_z0, 128, 128,
                                                          4, 8, 0, 4, 4, 0);
  k_transpose<<<dim3(4, 4, 40), dim3(32, 8), 0, stream>>>(W_rel, wt_z1, 128, 128,
                                                          4, 8, 4, 4, 4, 0);
  k_transpose<<<dim3(8, 8, 10), dim3(32, 8), 0, stream>>>(W_u1, wt_u1, 256, 256,
                                                          1, 1, 0, 1, 1, 0);
  k_fold_wu1<<<dim3(8, 10), dim3(256), 0, stream>>>(W_u1, W_loop, wt_u1);
  k_transpose<<<dim3(4, 12, 10), dim3(32, 8), 0, stream>>>(W_u2, wt_u2, 384, 128,
                                                           1, 1, 0, 1, 1, 0);
  k_cvt<<<(N * 64 / 4 + 255) / 256, 256, 0, stream>>>(feats, featsb, N * 64 / 4);

  // --- dst-CSR build ---
  k_zero<<<128, 256, 0, stream>>>(rowCnt, N);
  k_hist_row<<<(E + 255) / 256, 256, 0, stream>>>(dst, E, rowCnt);
  k_scan_part<<<256, 256, 0, stream>>>(rowCnt, N, thrPre, blkSum);
  k_scan_mid<<<1, 256, 0, stream>>>(blkSum, 256, N, blkOff, rowStart);
  k_scan_fin<<<256, 256, 0, stream>>>(rowCnt, N, thrPre, blkOff, rowStart, rowCur);
  k_place_row<<<(E + 255) / 256, 256, 0, stream>>>(etype, src, dst, rowCur, epk, E);

  const dim3 blk(256);
  const int gm = (N + 127) / 128;
  const dim3 gseg((N + 15) / 16);

  // input projection: x0 = tanh(featsb @ W_in + b_in)
  gemm_lds<64, 64, 2><<<dim3(1, gm), blk, 0, stream>>>(
      featsb, featsb, wt_in, b_in, xb0, nullptr, N, HID, 1);

  for (int l = 0; l < NL; l++) {
    const __bf16* xin = (l & 1) ? xb1 : xb0;
    __bf16* xout = (l & 1) ? xb0 : xb1;

    // pass 0: Z = xin @ [W_0..3]  (N x 512; W_loop folded into wt_u1)
    gemm_lds<128, 128, 2><<<dim3(4, gm), blk, 0, stream>>>(
        xin, xin, wt_z0 + (size_t)l * 4 * TS, nullptr, Z, nullptr, N, 512, 0);
    // seg0: msg = b_rel + sum(r<4) edges
    seg_sum<<<gseg, blk, 0, stream>>>(Z, rowStart, epk, b_rel + (size_t)l * HID,
                                      msgb, N, 0, 512);
    // pass 1: Z = xin @ [W_4..7]  (N x 512)
    gemm_lds<128, 128, 2><<<dim3(4, gm), blk, 0, stream>>>(
        xin, xin, wt_z1 + (size_t)l * 4 * TS, nullptr, Z, nullptr, N, 512, 0);
    // seg1: msg += sum(r>=4) edges
    seg_sum<<<gseg, blk, 0, stream>>>(Z, rowStart, epk, nullptr,
                                      msgb, N, 4, 512);

    // fused U1+U2: x' = tanh([x | tanh([x|msg]@Wu1e+b)] @ Wu2 + b)
    fused_u<<<dim3(gm), blk, 0, stream>>>(
        xin, msgb,
        wt_u1 + (size_t)l * 256 * 256, b_u1 + (size_t)l * 256,
        wt_u2 + (size_t)l * HID * 384, b_u2 + (size_t)l * HID,
        (l == NL - 1) ? nullptr : xout,
        (l == NL - 1) ? (float*)d_out : nullptr,
        N);
  }
}

// Round 9
// 2663.283 us; speedup vs baseline: 1.2546x; 1.1157x over previous
//
#include <hip/hip_runtime.h>
#include <cstddef>

// ---------------------------------------------------------------------------
// RelGraphConv GNN, 10 layers. Round 17: 512-thread 256x128 DMA GEMM.
//   R16 fused_u regressed (1 block/CU, msg was L3-hot anyway) -> reverted to
//   separate U1/U2. R14 analysis: GEMM time ~ #K-step-drains x (outstanding
//   bytes / eff BW). Lever: more outstanding per CU at same block count.
//   R17 gemm_lds: 512 threads, 256-row x 128-col C-tile, BK=32 dbuf staged
//   via global_load_lds (A 16 KB + B 8 KB per step), 48 KB LDS -> 3
//   blocks/CU, ~72 KB reads outstanding/CU (+60% vs R14), chip-wide step
//   count halves. Per-wave inner loop identical to the proven R12 kernel.
// Keeps: W_loop fold into W_u1, col-fastest grid, fast_tanh, parallel scan.
// N=100000, E=600000, F=64, H=128, R=8.
// ---------------------------------------------------------------------------

#define HID 128
#define NREL 8
#define NL 10

typedef __attribute__((ext_vector_type(8))) __bf16 bf16x8;
typedef __attribute__((ext_vector_type(4))) float f32x4;

__device__ __forceinline__ float fast_tanh(float x) {
  float cx = fminf(fmaxf(x, -10.f), 10.f);
  float z = exp2f(cx * 2.8853900817779268f);
  return (z - 1.f) * __builtin_amdgcn_rcpf(z + 1.f);
}

// --- batched transpose + f32->bf16: tile z: W[zi][K][Nc] -> Wt[zo][Nc][K] ---
__global__ __launch_bounds__(256) void k_transpose(const float* __restrict__ W,
                                                   __bf16* __restrict__ Wt,
                                                   int K, int Nc,
                                                   int inDiv, int inScale, int inOff,
                                                   int outDiv, int outScale, int outOff) {
  __shared__ float t[32][33];
  int z = blockIdx.z;
  int zi = (z / inDiv) * inScale + (z % inDiv) + inOff;
  int zo = (z / outDiv) * outScale + (z % outDiv) + outOff;
  const float* Wz = W + (size_t)zi * K * Nc;
  __bf16* Wtz = Wt + (size_t)zo * K * Nc;
  int n0 = blockIdx.x * 32, k0 = blockIdx.y * 32;
#pragma unroll
  for (int i = 0; i < 4; i++) {
    int k = k0 + threadIdx.y + i * 8;
    int n = n0 + threadIdx.x;
    t[threadIdx.y + i * 8][threadIdx.x] = Wz[(size_t)k * Nc + n];
  }
  __syncthreads();
#pragma unroll
  for (int i = 0; i < 4; i++) {
    int n = n0 + threadIdx.y + i * 8;
    int k = k0 + threadIdx.x;
    Wtz[(size_t)n * K + k] = (__bf16)t[threadIdx.x][threadIdx.y + i * 8];
  }
}

// --- fold W_loop into wt_u1 (k<128 rows): wt[n][k] = Wu1[k][n] + sum_j
//     Wloop[k][j]*Wu1[128+j][n]. Runs AFTER k_transpose(W_u1).
__global__ __launch_bounds__(256) void k_fold_wu1(const float* __restrict__ Wu1,
                                                  const float* __restrict__ Wloop,
                                                  __bf16* __restrict__ wt) {
  int l = blockIdx.y;
  int n0 = blockIdx.x * 32;
  const float* wu1 = Wu1 + (size_t)l * 256 * 256;
  const float* wl = Wloop + (size_t)l * 128 * 128;
  __bf16* wtl = wt + (size_t)l * 256 * 256;
  __shared__ float bot[128][33];
  for (int t = threadIdx.x; t < 128 * 32; t += 256) {
    int j = t >> 5, c = t & 31;
    bot[j][c] = wu1[(size_t)(128 + j) * 256 + n0 + c];
  }
  __syncthreads();
  int k = threadIdx.x & 127;
  int half = threadIdx.x >> 7;
  float acc[16];
#pragma unroll
  for (int c = 0; c < 16; c++) acc[c] = 0.f;
  for (int j = 0; j < 128; j++) {
    float w = wl[(size_t)k * 128 + j];
#pragma unroll
    for (int c = 0; c < 16; c++) acc[c] += w * bot[j][half * 16 + c];
  }
#pragma unroll
  for (int c = 0; c < 16; c++) {
    int n = n0 + half * 16 + c;
    wtl[(size_t)n * 256 + k] = (__bf16)(wu1[(size_t)k * 256 + n] + acc[c]);
  }
}

// --- f32 -> bf16 elementwise (n4 = count/4) ---
__global__ __launch_bounds__(256) void k_cvt(const float* __restrict__ x,
                                             __bf16* __restrict__ y, int n4) {
  int i = blockIdx.x * 256 + threadIdx.x;
  if (i < n4) {
    float4 f = ((const float4*)x)[i];
    __bf16 o[4] = {(__bf16)f.x, (__bf16)f.y, (__bf16)f.z, (__bf16)f.w};
    *(uint2*)(y + (size_t)i * 4) = *(uint2*)o;
  }
}

// ===================== dst-CSR build (once per launch) ======================
__global__ __launch_bounds__(256) void k_zero(int* __restrict__ p, int n) {
  for (int i = blockIdx.x * 256 + threadIdx.x; i < n; i += gridDim.x * 256) p[i] = 0;
}

__global__ __launch_bounds__(256) void k_hist_row(const int* __restrict__ dst,
                                                  int E, int* __restrict__ rowCnt) {
  int e = blockIdx.x * 256 + threadIdx.x;
  if (e < E) atomicAdd(&rowCnt[dst[e]], 1);
}

// --- hierarchical prefix scan over rowCnt[0..nb) ---------------------------
__global__ __launch_bounds__(256) void k_scan_part(const int* __restrict__ rowCnt,
                                                   int nb, int* __restrict__ thrPre,
                                                   int* __restrict__ blkSum) {
  __shared__ int sdata[256];
  int tid = threadIdx.x;
  int gtid = blockIdx.x * 256 + tid;
  int tot = gridDim.x * 256;
  int chunk = (nb + tot - 1) / tot;
  int lo = gtid * chunk, hi = min(nb, lo + chunk);
  int s = 0;
  for (int i = lo; i < hi; i++) s += rowCnt[i];
  sdata[tid] = s;
  __syncthreads();
#pragma unroll
  for (int off = 1; off < 256; off <<= 1) {
    int t = (tid >= off) ? sdata[tid - off] : 0;
    __syncthreads();
    sdata[tid] += t;
    __syncthreads();
  }
  thrPre[gtid] = sdata[tid] - s;
  if (tid == 255) blkSum[blockIdx.x] = sdata[255];
}

__global__ __launch_bounds__(256) void k_scan_mid(const int* __restrict__ blkSum,
                                                  int nblk, int nb,
                                                  int* __restrict__ blkOff,
                                                  int* __restrict__ rowStart) {
  __shared__ int part[256];
  int tid = threadIdx.x;
  part[tid] = (tid < nblk) ? blkSum[tid] : 0;
  __syncthreads();
  if (tid == 0) {
    int a = 0;
    for (int i = 0; i < nblk; i++) { int v = part[i]; part[i] = a; a += v; }
    rowStart[nb] = a;
  }
  __syncthreads();
  if (tid < nblk) blkOff[tid] = part[tid];
}

__global__ __launch_bounds__(256) void k_scan_fin(const int* __restrict__ rowCnt,
                                                  int nb,
                                                  const int* __restrict__ thrPre,
                                                  const int* __restrict__ blkOff,
                                                  int* __restrict__ rowStart,
                                                  int* __restrict__ rowCur) {
  int tid = threadIdx.x;
  int gtid = blockIdx.x * 256 + tid;
  int tot = gridDim.x * 256;
  int chunk = (nb + tot - 1) / tot;
  int lo = gtid * chunk, hi = min(nb, lo + chunk);
  int run = blkOff[blockIdx.x] + thrPre[gtid];
  for (int i = lo; i < hi; i++) {
    rowStart[i] = run;
    rowCur[i] = run;
    run += rowCnt[i];
  }
}

// pack: src (17 bits) | etype << 17
__global__ __launch_bounds__(256) void k_place_row(const int* __restrict__ et,
                                                   const int* __restrict__ src,
                                                   const int* __restrict__ dst,
                                                   int* __restrict__ rowCur,
                                                   int* __restrict__ epk, int E) {
  int e = blockIdx.x * 256 + threadIdx.x;
  if (e < E) {
    int p = atomicAdd(&rowCur[dst[e]], 1);
    epk[p] = src[e] | (et[e] << 17);
  }
}

// ========================= CSR segment-sum kernel ===========================
__global__ __launch_bounds__(256) void seg_sum(
    const __bf16* __restrict__ Z, const int* __restrict__ rowStart,
    const int* __restrict__ epk, const float* __restrict__ b_rel_l,
    __bf16* __restrict__ msgb, int N, int relBase, int zW) {
  int t16 = threadIdx.x & 15;
  int d = blockIdx.x * 16 + (threadIdx.x >> 4);
  if (d >= N) return;

  float acc[8];
  if (b_rel_l) {
#pragma unroll
    for (int z = 0; z < 8; z++) acc[z] = b_rel_l[t16 * 8 + z];
  } else {
    bf16x8 mv = *(const bf16x8*)(msgb + (size_t)d * HID + t16 * 8);
#pragma unroll
    for (int z = 0; z < 8; z++) acc[z] = (float)mv[z];
  }

  int lo = rowStart[d], hi = rowStart[d + 1];
  for (int e = lo; e < hi; e++) {
    int p = epk[e];
    int rr = (p >> 17) - relBase;
    if ((unsigned)rr < 4u) {
      bf16x8 v = *(const bf16x8*)(Z + (size_t)(p & 0x1FFFF) * zW + rr * HID + t16 * 8);
#pragma unroll
      for (int z = 0; z < 8; z++) acc[z] += (float)v[z];
    }
  }

  bf16x8 o;
#pragma unroll
  for (int z = 0; z < 8; z++) o[z] = (__bf16)acc[z];
  *(bf16x8*)(msgb + (size_t)d * HID + t16 * 8) = o;
}

// ---------------------------------------------------------------------------
// DMA-staged bf16 MFMA GEMM, 512 threads, 256x128 C-tile, BK=32 dbuf.
//   C = act(concat(A0,A1) @ B + bias). 8 waves: wave w owns the 64x64
//   sub-tile at (wr=(w>>1)*64, wc=(w&1)*64) -- per-wave inner loop identical
//   to the proven R12/R14 kernel (acc[4][4], 16 MFMA/step).
//   Staging per step: A 256x32 (16 KB, 1024 chunks, 2 DMA insts/wave),
//   B 128x32 (8 KB, 512 chunks, 1 DMA inst/wave). stage(k+1) before
//   compute(k); one __syncthreads per step (implicit vmcnt(0) drain).
//   grid: blockIdx.x = column tile (fastest), blockIdx.y = 256-row tile.
//   OOB tail rows read interior-workspace garbage (safe); stores guarded.
// ---------------------------------------------------------------------------
template <int K, int K0, int MINW>
__global__ __launch_bounds__(512, MINW) void gemm_lds(
    const __bf16* __restrict__ A0, const __bf16* __restrict__ A1,
    const __bf16* __restrict__ Bt, const float* __restrict__ bias,
    __bf16* __restrict__ Cb, float* __restrict__ Cf,
    int M, int Nc, int act) {
  constexpr int NS = K / 32;
  constexpr int NS0 = K0 / 32;
  constexpr int K1 = (K - K0) > 0 ? (K - K0) : 1;
  __shared__ __bf16 As[2][256][32];
  __shared__ __bf16 Bs[2][128][32];

  const int tid = threadIdx.x;
  const int m0 = blockIdx.y * 256;
  const int bn0 = blockIdx.x * 128;
  const int w = tid >> 6;       // 0..7
  const int lane = tid & 63;

  // A: 1024 chunks (16B): chunk c -> row c>>2, slot c&3. wave w: c = w*128 + j*64 + lane
  const int cA0 = w * 128 + lane;
  const int rA0 = cA0 >> 2, sA0 = cA0 & 3;
  const int cA1 = cA0 + 64;
  const int rA1 = cA1 >> 2, sA1 = cA1 & 3;
  // B: 512 chunks: wave w: c = w*64 + lane
  const int cB = w * 64 + lane;
  const int rB = cB >> 2, sB = cB & 3;

  auto stage_step = [&](int b, int ks) {
    // B tile (rows = output cols, stride K): 1 inst/wave
    {
      const __bf16* g = Bt + (size_t)(bn0 + rB) * K + ks * 32 + sB * 8;
      __builtin_amdgcn_global_load_lds(
          (const __attribute__((address_space(1))) void*)g,
          (__attribute__((address_space(3))) void*)(&Bs[b][0][0] + (size_t)w * 512),
          16, 0, 0);
    }
    // A tile: 2 insts/wave; concat segment select (wave-uniform per step)
    if (ks < NS0) {
      const __bf16* g0 = A0 + (size_t)(m0 + rA0) * K0 + ks * 32 + sA0 * 8;
      __builtin_amdgcn_global_load_lds(
          (const __attribute__((address_space(1))) void*)g0,
          (__attribute__((address_space(3))) void*)(&As[b][0][0] + (size_t)(w * 2 + 0) * 512),
          16, 0, 0);
      const __bf16* g1 = A0 + (size_t)(m0 + rA1) * K0 + ks * 32 + sA1 * 8;
      __builtin_amdgcn_global_load_lds(
          (const __attribute__((address_space(1))) void*)g1,
          (__attribute__((address_space(3))) void*)(&As[b][0][0] + (size_t)(w * 2 + 1) * 512),
          16, 0, 0);
    } else {
      const __bf16* g0 = A1 + (size_t)(m0 + rA0) * K1 + (ks - NS0) * 32 + sA0 * 8;
      __builtin_amdgcn_global_load_lds(
          (const __attribute__((address_space(1))) void*)g0,
          (__attribute__((address_space(3))) void*)(&As[b][0][0] + (size_t)(w * 2 + 0) * 512),
          16, 0, 0);
      const __bf16* g1 = A1 + (size_t)(m0 + rA1) * K1 + (ks - NS0) * 32 + sA1 * 8;
      __builtin_amdgcn_global_load_lds(
          (const __attribute__((address_space(1))) void*)g1,
          (__attribute__((address_space(3))) void*)(&As[b][0][0] + (size_t)(w * 2 + 1) * 512),
          16, 0, 0);
    }
  };

  const int ml = lane & 15, q = lane >> 4;
  const int wr = (w >> 1) * 64;   // 0,64,128,192
  const int wc = (w & 1) * 64;    // 0,64

  f32x4 acc[4][4];
#pragma unroll
  for (int i = 0; i < 4; i++)
#pragma unroll
    for (int j = 0; j < 4; j++)
#pragma unroll
      for (int r = 0; r < 4; r++) acc[i][j][r] = 0.f;

  stage_step(0, 0);
  __syncthreads();  // implicit vmcnt(0): buffer 0 ready

#pragma unroll
  for (int ks = 0; ks < NS; ks++) {
    const int cur = ks & 1;
    if (ks + 1 < NS) stage_step(cur ^ 1, ks + 1);  // async DMA, in flight
    bf16x8 af[4], bfr[4];
#pragma unroll
    for (int i = 0; i < 4; i++)
      af[i] = *(const bf16x8*)(&As[cur][wr + i * 16 + ml][q * 8]);
#pragma unroll
    for (int j = 0; j < 4; j++)
      bfr[j] = *(const bf16x8*)(&Bs[cur][wc + j * 16 + ml][q * 8]);
#pragma unroll
    for (int i = 0; i < 4; i++)
#pragma unroll
      for (int j = 0; j < 4; j++)
        acc[i][j] = __builtin_amdgcn_mfma_f32_16x16x32_bf16(af[i], bfr[j],
                                                            acc[i][j], 0, 0, 0);
    __syncthreads();  // drains stage(ks+1) DMA; protects buf reuse
  }

  // --- epilogue ---
#pragma unroll
  for (int i = 0; i < 4; i++) {
#pragma unroll
    for (int r = 0; r < 4; r++) {
      int grow = m0 + wr + i * 16 + q * 4 + r;
      if (grow >= M) continue;
#pragma unroll
      for (int j = 0; j < 4; j++) {
        int col = bn0 + wc + j * 16 + ml;
        float v = acc[i][j][r];
        if (bias) v += bias[col];
        if (act) v = fast_tanh(v);
        if (Cb) Cb[(size_t)grow * Nc + col] = (__bf16)v;
        if (Cf) Cf[(size_t)grow * Nc + col] = v;
      }
    }
  }
}

extern "C" void kernel_launch(void* const* d_in, const int* in_sizes, int n_in,
                              void* d_out, int out_size, void* d_ws, size_t ws_size,
                              hipStream_t stream) {
  const float* feats  = (const float*)d_in[0];
  const int*   src    = (const int*)d_in[1];
  const int*   dst    = (const int*)d_in[2];
  const int*   etype  = (const int*)d_in[3];
  const float* W_in   = (const float*)d_in[4];
  const float* b_in   = (const float*)d_in[5];
  const float* W_rel  = (const float*)d_in[6];
  const float* W_loop = (const float*)d_in[7];
  const float* b_rel  = (const float*)d_in[8];
  const float* W_u1   = (const float*)d_in[9];
  const float* b_u1   = (const float*)d_in[10];
  const float* W_u2   = (const float*)d_in[11];
  const float* b_u2   = (const float*)d_in[12];

  const int E = in_sizes[1];
  const int N = in_sizes[0] / 64;
  const int TS = HID * HID;

  // --- workspace layout (~210 MB) ---
  __bf16* xb0  = (__bf16*)d_ws;                       // N*128
  __bf16* xb1  = xb0 + (size_t)N * HID;               // N*128
  __bf16* msgb = xb1 + (size_t)N * HID;               // N*128
  __bf16* U    = msgb + (size_t)N * HID;              // N*640 (Z | mid | featsb)
  __bf16* Z    = U;
  __bf16* mid  = U;
  __bf16* featsb = U;
  __bf16* wt_in = U + (size_t)N * 640;                // [128][64]
  __bf16* wt_z0 = wt_in + 128 * 64;                   // [10][4][128][128]
  __bf16* wt_z1 = wt_z0 + (size_t)10 * 4 * TS;        // [10][4][128][128]
  __bf16* wt_u1 = wt_z1 + (size_t)10 * 4 * TS;        // [10][256][256]
  __bf16* wt_u2 = wt_u1 + (size_t)10 * 256 * 256;     // [10][128][384]
  int* rowCnt   = (int*)(wt_u2 + (size_t)10 * 128 * 384); // N
  int* rowStart = rowCnt + N;                         // N+1
  int* rowCur   = rowStart + N + 1;                   // N
  int* epk      = rowCur + N;                         // E
  int* thrPre   = epk + E;                            // 256*256
  int* blkSum   = thrPre + 256 * 256;                 // 256
  int* blkOff   = blkSum + 256;                       // 256

  // --- weight transpose+convert ---
  k_transpose<<<dim3(4, 2, 1), dim3(32, 8), 0, stream>>>(W_in, wt_in, 64, 128,
                                                         1, 1, 0, 1, 1, 0);
  k_transpose<<<dim3(4, 4, 40), dim3(32, 8), 0, stream>>>(W_rel, wt_z0, 128, 128,
                                                          4, 8, 0, 4, 4, 0);
  k_transpose<<<dim3(4, 4, 40), dim3(32, 8), 0, stream>>>(W_rel, wt_z1, 128, 128,
                                                          4, 8, 4, 4, 4, 0);
  k_transpose<<<dim3(8, 8, 10), dim3(32, 8), 0, stream>>>(W_u1, wt_u1, 256, 256,
                                                          1, 1, 0, 1, 1, 0);
  k_fold_wu1<<<dim3(8, 10), dim3(256), 0, stream>>>(W_u1, W_loop, wt_u1);
  k_transpose<<<dim3(4, 12, 10), dim3(32, 8), 0, stream>>>(W_u2, wt_u2, 384, 128,
                                                           1, 1, 0, 1, 1, 0);
  k_cvt<<<(N * 64 / 4 + 255) / 256, 256, 0, stream>>>(feats, featsb, N * 64 / 4);

  // --- dst-CSR build ---
  k_zero<<<128, 256, 0, stream>>>(rowCnt, N);
  k_hist_row<<<(E + 255) / 256, 256, 0, stream>>>(dst, E, rowCnt);
  k_scan_part<<<256, 256, 0, stream>>>(rowCnt, N, thrPre, blkSum);
  k_scan_mid<<<1, 256, 0, stream>>>(blkSum, 256, N, blkOff, rowStart);
  k_scan_fin<<<256, 256, 0, stream>>>(rowCnt, N, thrPre, blkOff, rowStart, rowCur);
  k_place_row<<<(E + 255) / 256, 256, 0, stream>>>(etype, src, dst, rowCur, epk, E);

  const dim3 blk(512);
  const int gm = (N + 255) / 256;
  const dim3 gseg((N + 15) / 16);

  // input projection: x0 = tanh(featsb @ W_in + b_in)
  gemm_lds<64, 64, 2><<<dim3(1, gm), blk, 0, stream>>>(
      featsb, featsb, wt_in, b_in, xb0, nullptr, N, HID, 1);

  for (int l = 0; l < NL; l++) {
    const __bf16* xin = (l & 1) ? xb1 : xb0;
    __bf16* xout = (l & 1) ? xb0 : xb1;

    // pass 0: Z = xin @ [W_0..3]  (N x 512; W_loop folded into wt_u1)
    gemm_lds<128, 128, 2><<<dim3(4, gm), blk, 0, stream>>>(
        xin, xin, wt_z0 + (size_t)l * 4 * TS, nullptr, Z, nullptr, N, 512, 0);
    // seg0: msg = b_rel + sum(r<4) edges
    seg_sum<<<gseg, dim3(256), 0, stream>>>(Z, rowStart, epk,
                                            b_rel + (size_t)l * HID,
                                            msgb, N, 0, 512);
    // pass 1: Z = xin @ [W_4..7]  (N x 512)
    gemm_lds<128, 128, 2><<<dim3(4, gm), blk, 0, stream>>>(
        xin, xin, wt_z1 + (size_t)l * 4 * TS, nullptr, Z, nullptr, N, 512, 0);
    // seg1: msg += sum(r>=4) edges
    seg_sum<<<gseg, dim3(256), 0, stream>>>(Z, rowStart, epk, nullptr,
                                            msgb, N, 4, 512);

    // mid = tanh([x | msg] @ Wu1_eff[l] + b_u1[l])   (mid aliases Z)
    gemm_lds<256, 128, 2><<<dim3(2, gm), blk, 0, stream>>>(
        xin, msgb, wt_u1 + (size_t)l * 256 * 256, b_u1 + (size_t)l * 256,
        mid, nullptr, N, 256, 1);

    // x' = tanh([x | mid] @ W_u2[l] + b_u2[l]); last layer -> f32 d_out
    gemm_lds<384, 128, 2><<<dim3(1, gm), blk, 0, stream>>>(
        xin, mid, wt_u2 + (size_t)l * HID * 384, b_u2 + (size_t)l * HID,
        (l == NL - 1) ? nullptr : xout,
        (l == NL - 1) ? (float*)d_out : nullptr,
        N, HID, 1);
  }
}

// Round 10
// 2612.598 us; speedup vs baseline: 1.2790x; 1.0194x over previous
//
#include <hip/hip_runtime.h>
#include <cstddef>

// ---------------------------------------------------------------------------
// RelGraphConv GNN, 10 layers. Round 18: minimal counted-vmcnt on R17 GEMM.
//   R17 proved outstanding-bytes is the BW lever (U1 82->59 us) but the
//   per-step __syncthreads (vmcnt(0) drain) still pays full DMA tail latency
//   every K-step (7.4 us/step measured vs ~1.4 us demand). R18: replace the
//   drain with the T4 counted sequence, UNCHANGED geometry (512 thr, 256x128
//   tile, BK=32, 2 buffers, 48 KB LDS):
//     per step: s_waitcnt vmcnt(3)  [own stage(k) landed, stage(k+1) = 3 DMA
//               insts stays in flight] ; s_barrier ; compute(k) ; s_barrier ;
//               stage(k+2) into freed buffer.
//   asm barriers carry "memory" clobbers so LDS ops can't be hoisted across.
//   (R13's counted-vmcnt regression changed 4 things at once - 3 bufs, 26%
//   occupancy, sched_barrier(0) pins; this graft changes only the drain.)
// Keeps: W_loop fold into W_u1, col-fastest grid, fast_tanh, parallel scan.
// N=100000, E=600000, F=64, H=128, R=8.
// ---------------------------------------------------------------------------

#define HID 128
#define NREL 8
#define NL 10

typedef __attribute__((ext_vector_type(8))) __bf16 bf16x8;
typedef __attribute__((ext_vector_type(4))) float f32x4;

__device__ __forceinline__ float fast_tanh(float x) {
  float cx = fminf(fmaxf(x, -10.f), 10.f);
  float z = exp2f(cx * 2.8853900817779268f);
  return (z - 1.f) * __builtin_amdgcn_rcpf(z + 1.f);
}

// --- batched transpose + f32->bf16: tile z: W[zi][K][Nc] -> Wt[zo][Nc][K] ---
__global__ __launch_bounds__(256) void k_transpose(const float* __restrict__ W,
                                                   __bf16* __restrict__ Wt,
                                                   int K, int Nc,
                                                   int inDiv, int inScale, int inOff,
                                                   int outDiv, int outScale, int outOff) {
  __shared__ float t[32][33];
  int z = blockIdx.z;
  int zi = (z / inDiv) * inScale + (z % inDiv) + inOff;
  int zo = (z / outDiv) * outScale + (z % outDiv) + outOff;
  const float* Wz = W + (size_t)zi * K * Nc;
  __bf16* Wtz = Wt + (size_t)zo * K * Nc;
  int n0 = blockIdx.x * 32, k0 = blockIdx.y * 32;
#pragma unroll
  for (int i = 0; i < 4; i++) {
    int k = k0 + threadIdx.y + i * 8;
    int n = n0 + threadIdx.x;
    t[threadIdx.y + i * 8][threadIdx.x] = Wz[(size_t)k * Nc + n];
  }
  __syncthreads();
#pragma unroll
  for (int i = 0; i < 4; i++) {
    int n = n0 + threadIdx.y + i * 8;
    int k = k0 + threadIdx.x;
    Wtz[(size_t)n * K + k] = (__bf16)t[threadIdx.x][threadIdx.y + i * 8];
  }
}

// --- fold W_loop into wt_u1 (k<128 rows): wt[n][k] = Wu1[k][n] + sum_j
//     Wloop[k][j]*Wu1[128+j][n]. Runs AFTER k_transpose(W_u1).
__global__ __launch_bounds__(256) void k_fold_wu1(const float* __restrict__ Wu1,
                                                  const float* __restrict__ Wloop,
                                                  __bf16* __restrict__ wt) {
  int l = blockIdx.y;
  int n0 = blockIdx.x * 32;
  const float* wu1 = Wu1 + (size_t)l * 256 * 256;
  const float* wl = Wloop + (size_t)l * 128 * 128;
  __bf16* wtl = wt + (size_t)l * 256 * 256;
  __shared__ float bot[128][33];
  for (int t = threadIdx.x; t < 128 * 32; t += 256) {
    int j = t >> 5, c = t & 31;
    bot[j][c] = wu1[(size_t)(128 + j) * 256 + n0 + c];
  }
  __syncthreads();
  int k = threadIdx.x & 127;
  int half = threadIdx.x >> 7;
  float acc[16];
#pragma unroll
  for (int c = 0; c < 16; c++) acc[c] = 0.f;
  for (int j = 0; j < 128; j++) {
    float w = wl[(size_t)k * 128 + j];
#pragma unroll
    for (int c = 0; c < 16; c++) acc[c] += w * bot[j][half * 16 + c];
  }
#pragma unroll
  for (int c = 0; c < 16; c++) {
    int n = n0 + half * 16 + c;
    wtl[(size_t)n * 256 + k] = (__bf16)(wu1[(size_t)k * 256 + n] + acc[c]);
  }
}

// --- f32 -> bf16 elementwise (n4 = count/4) ---
__global__ __launch_bounds__(256) void k_cvt(const float* __restrict__ x,
                                             __bf16* __restrict__ y, int n4) {
  int i = blockIdx.x * 256 + threadIdx.x;
  if (i < n4) {
    float4 f = ((const float4*)x)[i];
    __bf16 o[4] = {(__bf16)f.x, (__bf16)f.y, (__bf16)f.z, (__bf16)f.w};
    *(uint2*)(y + (size_t)i * 4) = *(uint2*)o;
  }
}

// ===================== dst-CSR build (once per launch) ======================
__global__ __launch_bounds__(256) void k_zero(int* __restrict__ p, int n) {
  for (int i = blockIdx.x * 256 + threadIdx.x; i < n; i += gridDim.x * 256) p[i] = 0;
}

__global__ __launch_bounds__(256) void k_hist_row(const int* __restrict__ dst,
                                                  int E, int* __restrict__ rowCnt) {
  int e = blockIdx.x * 256 + threadIdx.x;
  if (e < E) atomicAdd(&rowCnt[dst[e]], 1);
}

// --- hierarchical prefix scan over rowCnt[0..nb) ---------------------------
__global__ __launch_bounds__(256) void k_scan_part(const int* __restrict__ rowCnt,
                                                   int nb, int* __restrict__ thrPre,
                                                   int* __restrict__ blkSum) {
  __shared__ int sdata[256];
  int tid = threadIdx.x;
  int gtid = blockIdx.x * 256 + tid;
  int tot = gridDim.x * 256;
  int chunk = (nb + tot - 1) / tot;
  int lo = gtid * chunk, hi = min(nb, lo + chunk);
  int s = 0;
  for (int i = lo; i < hi; i++) s += rowCnt[i];
  sdata[tid] = s;
  __syncthreads();
#pragma unroll
  for (int off = 1; off < 256; off <<= 1) {
    int t = (tid >= off) ? sdata[tid - off] : 0;
    __syncthreads();
    sdata[tid] += t;
    __syncthreads();
  }
  thrPre[gtid] = sdata[tid] - s;
  if (tid == 255) blkSum[blockIdx.x] = sdata[255];
}

__global__ __launch_bounds__(256) void k_scan_mid(const int* __restrict__ blkSum,
                                                  int nblk, int nb,
                                                  int* __restrict__ blkOff,
                                                  int* __restrict__ rowStart) {
  __shared__ int part[256];
  int tid = threadIdx.x;
  part[tid] = (tid < nblk) ? blkSum[tid] : 0;
  __syncthreads();
  if (tid == 0) {
    int a = 0;
    for (int i = 0; i < nblk; i++) { int v = part[i]; part[i] = a; a += v; }
    rowStart[nb] = a;
  }
  __syncthreads();
  if (tid < nblk) blkOff[tid] = part[tid];
}

__global__ __launch_bounds__(256) void k_scan_fin(const int* __restrict__ rowCnt,
                                                  int nb,
                                                  const int* __restrict__ thrPre,
                                                  const int* __restrict__ blkOff,
                                                  int* __restrict__ rowStart,
                                                  int* __restrict__ rowCur) {
  int tid = threadIdx.x;
  int gtid = blockIdx.x * 256 + tid;
  int tot = gridDim.x * 256;
  int chunk = (nb + tot - 1) / tot;
  int lo = gtid * chunk, hi = min(nb, lo + chunk);
  int run = blkOff[blockIdx.x] + thrPre[gtid];
  for (int i = lo; i < hi; i++) {
    rowStart[i] = run;
    rowCur[i] = run;
    run += rowCnt[i];
  }
}

// pack: src (17 bits) | etype << 17
__global__ __launch_bounds__(256) void k_place_row(const int* __restrict__ et,
                                                   const int* __restrict__ src,
                                                   const int* __restrict__ dst,
                                                   int* __restrict__ rowCur,
                                                   int* __restrict__ epk, int E) {
  int e = blockIdx.x * 256 + threadIdx.x;
  if (e < E) {
    int p = atomicAdd(&rowCur[dst[e]], 1);
    epk[p] = src[e] | (et[e] << 17);
  }
}

// ========================= CSR segment-sum kernel ===========================
__global__ __launch_bounds__(256) void seg_sum(
    const __bf16* __restrict__ Z, const int* __restrict__ rowStart,
    const int* __restrict__ epk, const float* __restrict__ b_rel_l,
    __bf16* __restrict__ msgb, int N, int relBase, int zW) {
  int t16 = threadIdx.x & 15;
  int d = blockIdx.x * 16 + (threadIdx.x >> 4);
  if (d >= N) return;

  float acc[8];
  if (b_rel_l) {
#pragma unroll
    for (int z = 0; z < 8; z++) acc[z] = b_rel_l[t16 * 8 + z];
  } else {
    bf16x8 mv = *(const bf16x8*)(msgb + (size_t)d * HID + t16 * 8);
#pragma unroll
    for (int z = 0; z < 8; z++) acc[z] = (float)mv[z];
  }

  int lo = rowStart[d], hi = rowStart[d + 1];
  for (int e = lo; e < hi; e++) {
    int p = epk[e];
    int rr = (p >> 17) - relBase;
    if ((unsigned)rr < 4u) {
      bf16x8 v = *(const bf16x8*)(Z + (size_t)(p & 0x1FFFF) * zW + rr * HID + t16 * 8);
#pragma unroll
      for (int z = 0; z < 8; z++) acc[z] += (float)v[z];
    }
  }

  bf16x8 o;
#pragma unroll
  for (int z = 0; z < 8; z++) o[z] = (__bf16)acc[z];
  *(bf16x8*)(msgb + (size_t)d * HID + t16 * 8) = o;
}

// ---------------------------------------------------------------------------
// DMA-staged bf16 MFMA GEMM, 512 threads, 256x128 C-tile, BK=32, 2 buffers,
// counted-vmcnt pipeline (T4). Per wave each stage = exactly 3 DMA insts
// (1 B + 2 A) -> steady outstanding 6, wait to 3.
//   per step: vmcnt(3) [own stage(k) landed]; s_barrier [all waves'];
//             ds_read+MFMA(k); s_barrier [buf k free]; stage(k+2).
// ---------------------------------------------------------------------------
template <int K, int K0, int MINW>
__global__ __launch_bounds__(512, MINW) void gemm_lds(
    const __bf16* __restrict__ A0, const __bf16* __restrict__ A1,
    const __bf16* __restrict__ Bt, const float* __restrict__ bias,
    __bf16* __restrict__ Cb, float* __restrict__ Cf,
    int M, int Nc, int act) {
  constexpr int NS = K / 32;
  constexpr int NS0 = K0 / 32;
  constexpr int K1 = (K - K0) > 0 ? (K - K0) : 1;
  __shared__ __bf16 As[2][256][32];
  __shared__ __bf16 Bs[2][128][32];

  const int tid = threadIdx.x;
  const int m0 = blockIdx.y * 256;
  const int bn0 = blockIdx.x * 128;
  const int w = tid >> 6;       // 0..7
  const int lane = tid & 63;

  // A: 1024 chunks (16B): chunk c -> row c>>2, slot c&3. wave w: c = w*128 + j*64 + lane
  const int cA0 = w * 128 + lane;
  const int rA0 = cA0 >> 2, sA0 = cA0 & 3;
  const int cA1 = cA0 + 64;
  const int rA1 = cA1 >> 2, sA1 = cA1 & 3;
  // B: 512 chunks: wave w: c = w*64 + lane
  const int cB = w * 64 + lane;
  const int rB = cB >> 2, sB = cB & 3;

  auto stage_step = [&](int b, int ks) {
    // B tile (rows = output cols, stride K): 1 inst/wave
    {
      const __bf16* g = Bt + (size_t)(bn0 + rB) * K + ks * 32 + sB * 8;
      __builtin_amdgcn_global_load_lds(
          (const __attribute__((address_space(1))) void*)g,
          (__attribute__((address_space(3))) void*)(&Bs[b][0][0] + (size_t)w * 512),
          16, 0, 0);
    }
    // A tile: 2 insts/wave; concat segment select (wave-uniform per step)
    if (ks < NS0) {
      const __bf16* g0 = A0 + (size_t)(m0 + rA0) * K0 + ks * 32 + sA0 * 8;
      __builtin_amdgcn_global_load_lds(
          (const __attribute__((address_space(1))) void*)g0,
          (__attribute__((address_space(3))) void*)(&As[b][0][0] + (size_t)(w * 2 + 0) * 512),
          16, 0, 0);
      const __bf16* g1 = A0 + (size_t)(m0 + rA1) * K0 + ks * 32 + sA1 * 8;
      __builtin_amdgcn_global_load_lds(
          (const __attribute__((address_space(1))) void*)g1,
          (__attribute__((address_space(3))) void*)(&As[b][0][0] + (size_t)(w * 2 + 1) * 512),
          16, 0, 0);
    } else {
      const __bf16* g0 = A1 + (size_t)(m0 + rA0) * K1 + (ks - NS0) * 32 + sA0 * 8;
      __builtin_amdgcn_global_load_lds(
          (const __attribute__((address_space(1))) void*)g0,
          (__attribute__((address_space(3))) void*)(&As[b][0][0] + (size_t)(w * 2 + 0) * 512),
          16, 0, 0);
      const __bf16* g1 = A1 + (size_t)(m0 + rA1) * K1 + (ks - NS0) * 32 + sA1 * 8;
      __builtin_amdgcn_global_load_lds(
          (const __attribute__((address_space(1))) void*)g1,
          (__attribute__((address_space(3))) void*)(&As[b][0][0] + (size_t)(w * 2 + 1) * 512),
          16, 0, 0);
    }
  };

  const int ml = lane & 15, q = lane >> 4;
  const int wr = (w >> 1) * 64;   // 0,64,128,192
  const int wc = (w & 1) * 64;    // 0,64

  f32x4 acc[4][4];
#pragma unroll
  for (int i = 0; i < 4; i++)
#pragma unroll
    for (int j = 0; j < 4; j++)
#pragma unroll
      for (int r = 0; r < 4; r++) acc[i][j][r] = 0.f;

  // prologue: two stages in flight (6 DMA insts/wave)
  stage_step(0, 0);
  if (NS > 1) stage_step(1, 1);

#pragma unroll
  for (int ks = 0; ks < NS; ks++) {
    const int cur = ks & 1;
    // own stage(ks) landed; stage(ks+1)'s 3 DMAs stay in flight
    if (ks + 1 < NS) asm volatile("s_waitcnt vmcnt(3)" ::: "memory");
    else             asm volatile("s_waitcnt vmcnt(0)" ::: "memory");
    asm volatile("s_barrier" ::: "memory");  // all waves' stage(ks) landed

    bf16x8 af[4], bfr[4];
#pragma unroll
    for (int i = 0; i < 4; i++)
      af[i] = *(const bf16x8*)(&As[cur][wr + i * 16 + ml][q * 8]);
#pragma unroll
    for (int j = 0; j < 4; j++)
      bfr[j] = *(const bf16x8*)(&Bs[cur][wc + j * 16 + ml][q * 8]);
#pragma unroll
    for (int i = 0; i < 4; i++)
#pragma unroll
      for (int j = 0; j < 4; j++)
        acc[i][j] = __builtin_amdgcn_mfma_f32_16x16x32_bf16(af[i], bfr[j],
                                                            acc[i][j], 0, 0, 0);

    asm volatile("s_barrier" ::: "memory");  // all waves done reading buf[cur]
    if (ks + 2 < NS) stage_step(cur, ks + 2);  // refill freed buffer, stays in flight
  }

  // --- epilogue ---
#pragma unroll
  for (int i = 0; i < 4; i++) {
#pragma unroll
    for (int r = 0; r < 4; r++) {
      int grow = m0 + wr + i * 16 + q * 4 + r;
      if (grow >= M) continue;
#pragma unroll
      for (int j = 0; j < 4; j++) {
        int col = bn0 + wc + j * 16 + ml;
        float v = acc[i][j][r];
        if (bias) v += bias[col];
        if (act) v = fast_tanh(v);
        if (Cb) Cb[(size_t)grow * Nc + col] = (__bf16)v;
        if (Cf) Cf[(size_t)grow * Nc + col] = v;
      }
    }
  }
}

extern "C" void kernel_launch(void* const* d_in, const int* in_sizes, int n_in,
                              void* d_out, int out_size, void* d_ws, size_t ws_size,
                              hipStream_t stream) {
  const float* feats  = (const float*)d_in[0];
  const int*   src    = (const int*)d_in[1];
  const int*   dst    = (const int*)d_in[2];
  const int*   etype  = (const int*)d_in[3];
  const float* W_in   = (const float*)d_in[4];
  const float* b_in   = (const float*)d_in[5];
  const float* W_rel  = (const float*)d_in[6];
  const float* W_loop = (const float*)d_in[7];
  const float* b_rel  = (const float*)d_in[8];
  const float* W_u1   = (const float*)d_in[9];
  const float* b_u1   = (const float*)d_in[10];
  const float* W_u2   = (const float*)d_in[11];
  const float* b_u2   = (const float*)d_in[12];

  const int E = in_sizes[1];
  const int N = in_sizes[0] / 64;
  const int TS = HID * HID;

  // --- workspace layout (~210 MB) ---
  __bf16* xb0  = (__bf16*)d_ws;                       // N*128
  __bf16* xb1  = xb0 + (size_t)N * HID;               // N*128
  __bf16* msgb = xb1 + (size_t)N * HID;               // N*128
  __bf16* U    = msgb + (size_t)N * HID;              // N*640 (Z | mid | featsb)
  __bf16* Z    = U;
  __bf16* mid  = U;
  __bf16* featsb = U;
  __bf16* wt_in = U + (size_t)N * 640;                // [128][64]
  __bf16* wt_z0 = wt_in + 128 * 64;                   // [10][4][128][128]
  __bf16* wt_z1 = wt_z0 + (size_t)10 * 4 * TS;        // [10][4][128][128]
  __bf16* wt_u1 = wt_z1 + (size_t)10 * 4 * TS;        // [10][256][256]
  __bf16* wt_u2 = wt_u1 + (size_t)10 * 256 * 256;     // [10][128][384]
  int* rowCnt   = (int*)(wt_u2 + (size_t)10 * 128 * 384); // N
  int* rowStart = rowCnt + N;                         // N+1
  int* rowCur   = rowStart + N + 1;                   // N
  int* epk      = rowCur + N;                         // E
  int* thrPre   = epk + E;                            // 256*256
  int* blkSum   = thrPre + 256 * 256;                 // 256
  int* blkOff   = blkSum + 256;                       // 256

  // --- weight transpose+convert ---
  k_transpose<<<dim3(4, 2, 1), dim3(32, 8), 0, stream>>>(W_in, wt_in, 64, 128,
                                                         1, 1, 0, 1, 1, 0);
  k_transpose<<<dim3(4, 4, 40), dim3(32, 8), 0, stream>>>(W_rel, wt_z0, 128, 128,
                                                          4, 8, 0, 4, 4, 0);
  k_transpose<<<dim3(4, 4, 40), dim3(32, 8), 0, stream>>>(W_rel, wt_z1, 128, 128,
                                                          4, 8, 4, 4, 4, 0);
  k_transpose<<<dim3(8, 8, 10), dim3(32, 8), 0, stream>>>(W_u1, wt_u1, 256, 256,
                                                          1, 1, 0, 1, 1, 0);
  k_fold_wu1<<<dim3(8, 10), dim3(256), 0, stream>>>(W_u1, W_loop, wt_u1);
  k_transpose<<<dim3(4, 12, 10), dim3(32, 8), 0, stream>>>(W_u2, wt_u2, 384, 128,
                                                           1, 1, 0, 1, 1, 0);
  k_cvt<<<(N * 64 / 4 + 255) / 256, 256, 0, stream>>>(feats, featsb, N * 64 / 4);

  // --- dst-CSR build ---
  k_zero<<<128, 256, 0, stream>>>(rowCnt, N);
  k_hist_row<<<(E + 255) / 256, 256, 0, stream>>>(dst, E, rowCnt);
  k_scan_part<<<256, 256, 0, stream>>>(rowCnt, N, thrPre, blkSum);
  k_scan_mid<<<1, 256, 0, stream>>>(blkSum, 256, N, blkOff, rowStart);
  k_scan_fin<<<256, 256, 0, stream>>>(rowCnt, N, thrPre, blkOff, rowStart, rowCur);
  k_place_row<<<(E + 255) / 256, 256, 0, stream>>>(etype, src, dst, rowCur, epk, E);

  const dim3 blk(512);
  const int gm = (N + 255) / 256;
  const dim3 gseg((N + 15) / 16);

  // input projection: x0 = tanh(featsb @ W_in + b_in)
  gemm_lds<64, 64, 2><<<dim3(1, gm), blk, 0, stream>>>(
      featsb, featsb, wt_in, b_in, xb0, nullptr, N, HID, 1);

  for (int l = 0; l < NL; l++) {
    const __bf16* xin = (l & 1) ? xb1 : xb0;
    __bf16* xout = (l & 1) ? xb0 : xb1;

    // pass 0: Z = xin @ [W_0..3]  (N x 512; W_loop folded into wt_u1)
    gemm_lds<128, 128, 2><<<dim3(4, gm), blk, 0, stream>>>(
        xin, xin, wt_z0 + (size_t)l * 4 * TS, nullptr, Z, nullptr, N, 512, 0);
    // seg0: msg = b_rel + sum(r<4) edges
    seg_sum<<<gseg, dim3(256), 0, stream>>>(Z, rowStart, epk,
                                            b_rel + (size_t)l * HID,
                                            msgb, N, 0, 512);
    // pass 1: Z = xin @ [W_4..7]  (N x 512)
    gemm_lds<128, 128, 2><<<dim3(4, gm), blk, 0, stream>>>(
        xin, xin, wt_z1 + (size_t)l * 4 * TS, nullptr, Z, nullptr, N, 512, 0);
    // seg1: msg += sum(r>=4) edges
    seg_sum<<<gseg, dim3(256), 0, stream>>>(Z, rowStart, epk, nullptr,
                                            msgb, N, 4, 512);

    // mid = tanh([x | msg] @ Wu1_eff[l] + b_u1[l])   (mid aliases Z)
    gemm_lds<256, 128, 2><<<dim3(2, gm), blk, 0, stream>>>(
        xin, msgb, wt_u1 + (size_t)l * 256 * 256, b_u1 + (size_t)l * 256,
        mid, nullptr, N, 256, 1);

    // x' = tanh([x | mid] @ W_u2[l] + b_u2[l]); last layer -> f32 d_out
    gemm_lds<384, 128, 2><<<dim3(1, gm), blk, 0, stream>>>(
        xin, mid, wt_u2 + (size_t)l * HID * 384, b_u2 + (size_t)l * HID,
        (l == NL - 1) ? nullptr : xout,
        (l == NL - 1) ? (float*)d_out : nullptr,
        N, HID, 1);
  }
}